// Round 5
// baseline (155.594 us; speedup 1.0000x reference)
//
#include <hip/hip_runtime.h>
#include <hip/hip_bf16.h>

// B=8, H=W=1024, N=4096, R=8 -> d=17, patch=289, out (B,4096,578) fp32.
// p1[b,n,j] = image1[b, m1 + j%17 - 8, m0 + j//17 - 8]  (zero-pad OOB)
// p2[b,n,j] = image2[b, m3 + j%17 - 8, m2 + j//17 - 8]
// normalize each 289-vector: (p - mean) / (std_ddof1 + 1e-4)
//
// R5: R4 main kernel unchanged. Added a streaming LLC pre-warm prologue:
// both kernels at 2.7 TB/s were bound by HBM efficiency on random ~64-128B
// reads (43% of achievable). Images (64 MB) + output (74 MB) fit in the
// 256 MB Infinity Cache, so a sequential float4 sweep makes the gather
// LLC-resident and leaves only the streaming writes on DRAM.

#define IMG_H 1024
#define IMG_W 1024
#define NMATCH 4096
#define DPATCH 17
#define NPATCH 289
#define RAD 8

__global__ __launch_bounds__(256) void prewarm_kernel(
    const float* __restrict__ img1,
    const float* __restrict__ img2)
{
    const int tid = blockIdx.x * blockDim.x + threadIdx.x;
    const int nthreads = gridDim.x * blockDim.x;
    const float4* __restrict__ a = (const float4*)img1;
    const float4* __restrict__ b = (const float4*)img2;
    const int n4 = (8 * IMG_H * IMG_W) / 4;   // 2,097,152 float4 per image
    float s = 0.f;
    for (int i = tid; i < n4; i += nthreads) {
        float4 x = a[i];
        float4 y = b[i];
        s += x.x + x.y + x.z + x.w + y.x + y.y + y.z + y.w;
    }
    // consume s so the loads cannot be dead-code eliminated; no memory write
    asm volatile("" :: "v"(s));
}

__global__ __launch_bounds__(256) void extract_patch_kernel(
    const float* __restrict__ img1,
    const float* __restrict__ img2,
    const int* __restrict__ matches,
    float* __restrict__ out)
{
    __shared__ float smem[4 * NPATCH];   // 4 waves/block x 289 floats

    const int tid  = blockIdx.x * blockDim.x + threadIdx.x;
    const int wave = tid >> 6;          // global wave id: 0 .. 65535
    const int lane = tid & 63;
    const int pair  = wave >> 1;        // b*4096 + n : 0 .. 32767
    const int which = wave & 1;         // 0 -> img1, 1 -> img2
    const int wbase = (threadIdx.x >> 6) * NPATCH;

    // match coords (wave-uniform scalar loads, broadcast)
    const int* m = matches + pair * 4;
    const int mx = m[which ? 2 : 0];
    const int my = m[which ? 3 : 1];

    const int b = pair >> 12;           // pair / 4096
    const float* __restrict__ imgb =
        (which ? img2 : img1) + (size_t)b * (IMG_H * IMG_W);

    // ---- coalesced load phase ----
    const int g = lane / DPATCH;        // row-group 0..2 (3 = idle lanes 51..63)
    const int c = lane - g * DPATCH;    // column within patch row segment, 0..16
    const int ix = mx + c - RAD;        // image column (contiguous across lanes)
    const bool col_ok = (g < 3) && ((unsigned)ix < IMG_W);

    float sum = 0.f, sumsq = 0.f;
#pragma unroll
    for (int it = 0; it < 6; ++it) {
        const int r = it * 3 + g;       // patch row 0..17 (17 -> idle)
        float val = 0.f;
        if (g < 3 && r < DPATCH) {
            const int iy = my + r - RAD;
            if (col_ok && (unsigned)iy < IMG_H) {
                val = imgb[iy * IMG_W + ix];
            }
            smem[wbase + r + DPATCH * c] = val;   // output position j = r + 17c
        }
        sum   += val;
        sumsq += val * val;
    }

    // wave-64 butterfly reduction
#pragma unroll
    for (int off = 32; off > 0; off >>= 1) {
        sum   += __shfl_xor(sum,   off, 64);
        sumsq += __shfl_xor(sumsq, off, 64);
    }

    const float mean = sum * (1.0f / 289.0f);
    float var = (sumsq - 289.0f * mean * mean) * (1.0f / 288.0f);
    var = fmaxf(var, 0.0f);
    const float inv = 1.0f / (sqrtf(var) + 1e-4f);

    // ---- coalesced store phase (LDS read in output order) ----
    float* __restrict__ o = out + (size_t)pair * 578 + which * NPATCH;
#pragma unroll
    for (int k = 0; k < 5; ++k) {
        const int j = lane + (k << 6);
        if (j < NPATCH) {
            o[j] = (smem[wbase + j] - mean) * inv;
        }
    }
}

extern "C" void kernel_launch(void* const* d_in, const int* in_sizes, int n_in,
                              void* d_out, int out_size, void* d_ws, size_t ws_size,
                              hipStream_t stream) {
    const float* img1  = (const float*)d_in[0];
    const float* img2  = (const float*)d_in[1];
    const int* matches = (const int*)d_in[2];
    float* out         = (float*)d_out;

    // LLC pre-warm: sequential sweep of both images (64 MB) at streaming BW
    hipLaunchKernelGGL(prewarm_kernel, dim3(2048), dim3(256), 0, stream,
                       img1, img2);

    // 8 * 4096 pairs * 2 images = 65536 waves; 4 waves (patches) per block
    const int n_waves = 8 * NMATCH * 2;
    dim3 block(256);
    dim3 grid(n_waves * 64 / 256);
    hipLaunchKernelGGL(extract_patch_kernel, grid, block, 0, stream,
                       img1, img2, matches, out);
}

// Round 6
// 153.348 us; speedup vs baseline: 1.0146x; 1.0146x over previous
//
#include <hip/hip_runtime.h>
#include <hip/hip_bf16.h>

// B=8, H=W=1024, N=4096, R=8 -> d=17, patch=289, out (B,4096,578) fp32.
// p1[b,n,j] = image1[b, m1 + j%17 - 8, m0 + j//17 - 8]  (zero-pad OOB)
// p2[b,n,j] = image2[b, m3 + j%17 - 8, m2 + j//17 - 8]
// normalize each 289-vector: (p - mean) / (std_ddof1 + 1e-4)
//
// R6: extract is read-LATENCY bound (R4 coalescing was neutral; R5 LLC
// prewarm cut extract 60->~46 by cutting latency, not bytes). Fix = MLP:
// each wave now owns 4 patches (2 pairs x 2 images) and issues all 24
// independent row-segment loads up front; the 8 reduction chains are
// interleaved; LDS transpose + coalesced nontemporal stores (nt keeps the
// 74 MB write stream from evicting the warmed images out of LLC).

#define IMG_H 1024
#define IMG_W 1024
#define NMATCH 4096
#define DPATCH 17
#define NPATCH 289
#define RAD 8
#define HW (IMG_H * IMG_W)

__global__ __launch_bounds__(256) void prewarm_kernel(
    const float* __restrict__ img1,
    const float* __restrict__ img2)
{
    const int tid = blockIdx.x * blockDim.x + threadIdx.x;
    const int nthreads = gridDim.x * blockDim.x;
    const float4* __restrict__ a = (const float4*)img1;
    const float4* __restrict__ b = (const float4*)img2;
    const int n4 = (8 * HW) / 4;
    float s = 0.f;
    for (int i = tid; i < n4; i += nthreads) {
        float4 x = a[i];
        float4 y = b[i];
        s += x.x + x.y + x.z + x.w + y.x + y.y + y.z + y.w;
    }
    asm volatile("" :: "v"(s));   // keep loads alive, no memory write
}

__global__ __launch_bounds__(256) void extract_patch_kernel(
    const float* __restrict__ img1,
    const float* __restrict__ img2,
    const int* __restrict__ matches,
    float* __restrict__ out)
{
    // 4 waves/block x 4 patches/wave x 289 floats = 18496 B
    __shared__ float smem[4 * 4 * NPATCH];

    const int tid   = blockIdx.x * blockDim.x + threadIdx.x;
    const int wave  = tid >> 6;            // 0 .. 16383
    const int lane  = tid & 63;
    const int wslot = threadIdx.x >> 6;    // 0..3
    const int pair0 = wave << 1;           // even; patches = pairs {pair0, pair0+1} x {img1, img2}

    // load-phase lane mapping: 3 groups x 17 lanes, lanes 51..63 idle
    const int g = lane / DPATCH;           // 0..2 active, 3 idle
    const int c = lane - g * DPATCH;       // 0..16 column within row segment
    const bool active = (g < 3);

    const int b = pair0 >> 12;             // 4096 pairs per batch; pair0,pair0+1 same b
    const float* __restrict__ base1 = img1 + (size_t)b * HW;
    const float* __restrict__ base2 = img2 + (size_t)b * HW;

    int mx[4], my[4];
#pragma unroll
    for (int t = 0; t < 4; ++t) {
        const int pr = pair0 + (t >> 1);
        const int wh = t & 1;
        mx[t] = matches[pr * 4 + (wh ? 2 : 0)];
        my[t] = matches[pr * 4 + (wh ? 3 : 1)];
    }

    // ---- issue all 24 independent loads up front (branchless, select-to-0) ----
    float v[4][6];
#pragma unroll
    for (int t = 0; t < 4; ++t) {
        const float* __restrict__ ib = (t & 1) ? base2 : base1;
        const int ix = mx[t] + c - RAD;
#pragma unroll
        for (int it = 0; it < 6; ++it) {
            const int r  = it * 3 + g;     // patch row; r==17 only at (it=5,g=2)
            const int iy = my[t] + r - RAD;
            const bool ok = active && (r < DPATCH) &&
                            ((unsigned)ix < IMG_W) && ((unsigned)iy < IMG_H);
            const int off = ok ? (iy * IMG_W + ix) : 0;   // inactive -> line 0 (broadcast)
            const float val = ib[off];
            v[t][it] = ok ? val : 0.f;
        }
    }

    // ---- LDS transpose: value lands at output position j = r + 17*c ----
#pragma unroll
    for (int t = 0; t < 4; ++t) {
#pragma unroll
        for (int it = 0; it < 6; ++it) {
            const int r = it * 3 + g;
            if (active && r < DPATCH) {
                smem[(wslot * 4 + t) * NPATCH + r + DPATCH * c] = v[t][it];
            }
        }
    }

    // ---- per-patch partial sums, then 8 interleaved shuffle chains ----
    float s[4], q[4];
#pragma unroll
    for (int t = 0; t < 4; ++t) {
        s[t] = 0.f; q[t] = 0.f;
#pragma unroll
        for (int it = 0; it < 6; ++it) {
            s[t] += v[t][it];
            q[t] += v[t][it] * v[t][it];
        }
    }
#pragma unroll
    for (int off = 32; off > 0; off >>= 1) {
#pragma unroll
        for (int t = 0; t < 4; ++t) {
            s[t] += __shfl_xor(s[t], off, 64);
            q[t] += __shfl_xor(q[t], off, 64);
        }
    }

    // ---- normalize + coalesced nontemporal stores ----
    // patch t output offset: pair*578 + which*289 = pair0*578 + t*289
    float* __restrict__ o0 = out + (size_t)pair0 * 578;
#pragma unroll
    for (int t = 0; t < 4; ++t) {
        const float mean = s[t] * (1.0f / 289.0f);
        float var = (q[t] - 289.0f * mean * mean) * (1.0f / 288.0f);
        var = fmaxf(var, 0.0f);
        const float inv = 1.0f / (sqrtf(var) + 1e-4f);
        float* __restrict__ o = o0 + t * NPATCH;
#pragma unroll
        for (int k = 0; k < 5; ++k) {
            const int j = lane + (k << 6);
            if (j < NPATCH) {
                const float z = (smem[(wslot * 4 + t) * NPATCH + j] - mean) * inv;
                __builtin_nontemporal_store(z, &o[j]);
            }
        }
    }
}

extern "C" void kernel_launch(void* const* d_in, const int* in_sizes, int n_in,
                              void* d_out, int out_size, void* d_ws, size_t ws_size,
                              hipStream_t stream) {
    const float* img1  = (const float*)d_in[0];
    const float* img2  = (const float*)d_in[1];
    const int* matches = (const int*)d_in[2];
    float* out         = (float*)d_out;

    // LLC pre-warm: sequential sweep of both images (64 MB) at streaming BW
    hipLaunchKernelGGL(prewarm_kernel, dim3(2048), dim3(256), 0, stream,
                       img1, img2);

    // 65536 patches / 4 per wave = 16384 waves = 4096 blocks of 256
    hipLaunchKernelGGL(extract_patch_kernel, dim3(4096), dim3(256), 0, stream,
                       img1, img2, matches, out);
}